// Round 1
// baseline (242.640 us; speedup 1.0000x reference)
//
#include <hip/hip_runtime.h>
#include <math.h>

// B=8192 rows, F=3072 features, block=3. One workgroup per row.
//
// v2: kill per-instruction cache-line amplification. The old layout gave each
// thread 12 CONTIGUOUS floats -> every float4 load/store had a 48B lane
// stride, so each of the 3 loads per array touched the SAME 48 cache lines
// (3x L1/TA line-transactions; kernel sat at 2.3 TB/s with all pipes <40%).
//
// New mapping: thread t owns blocks {t, t+256c} (c=0..3) -> 12B lane stride,
// fully contiguous across the wave.
//   loads : overlapping dwordx4 at float offset 3b (use .xyz); chunk 3 loads
//           at 3b-1 (use .yzw) so the 16B window ends exactly at the row end.
//           Every 64B line is touched by exactly one instruction.
//   stores: y staged through LDS (scalar writes at stride 3 -> gcd(3,32)=1 ->
//           free 2-way banking), then 3 coalesced float4 stores.
#define BATCH 8192
#define FEAT  3072
#define TPB   256

// Analytic log|det J| for the d=3 Moebius block:
//   T(z) = w + (1-|w|^2)(z+w)/|z+w|^2 is conformal, DT = lambda*(I-2nn^T),
//   lambda = (1-|w|^2)/|z+w|^2 = c. For y = r*T(x/r): |det J| = c^(d-1) = c^2.
//   sum log|det| = 2*ln2 * sum log2(c).

__global__ __launch_bounds__(TPB, 8)
void moebius_kernel(const float* __restrict__ x,
                    const float* __restrict__ w,
                    float* __restrict__ out) {
    __shared__ __align__(16) float sy[FEAT];   // transposed y staging (12 KB)
    __shared__ float swred[TPB / 64];

    const int row = blockIdx.x;
    const int tid = threadIdx.x;
    const size_t rbase = (size_t)row * FEAT;
    const float* __restrict__ xr = x + rbase;
    const float* __restrict__ wr = w + rbase;

    // All 8 loads issued up front (8 KB/wave in flight), all lane-contiguous.
    float4 xv0, xv1, xv2, xv3, wv0, wv1, wv2, wv3;
    {
        const int o0 = 3 * tid;            // block t      : floats [3t,   3t+4)
        const int o1 = 3 * tid + 768;      // block t+256
        const int o2 = 3 * tid + 1536;     // block t+512
        const int o3 = 3 * tid + 2303;     // block t+768  : floats [3b-1, 3b+3)
        xv0 = *(const float4*)(xr + o0);
        xv1 = *(const float4*)(xr + o1);
        xv2 = *(const float4*)(xr + o2);
        xv3 = *(const float4*)(xr + o3);
        wv0 = *(const float4*)(wr + o0);
        wv1 = *(const float4*)(wr + o1);
        wv2 = *(const float4*)(wr + o2);
        wv3 = *(const float4*)(wr + o3);
    }

    float lsum = 0.0f;   // accumulates log2(c)

    #pragma unroll
    for (int c = 0; c < 4; ++c) {
        float x0, x1, x2, w0, w1, w2;
        if (c == 0)      { x0 = xv0.x; x1 = xv0.y; x2 = xv0.z;
                           w0 = wv0.x; w1 = wv0.y; w2 = wv0.z; }
        else if (c == 1) { x0 = xv1.x; x1 = xv1.y; x2 = xv1.z;
                           w0 = wv1.x; w1 = wv1.y; w2 = wv1.z; }
        else if (c == 2) { x0 = xv2.x; x1 = xv2.y; x2 = xv2.z;
                           w0 = wv2.x; w1 = wv2.y; w2 = wv2.z; }
        else             { x0 = xv3.y; x1 = xv3.z; x2 = xv3.w;   // offset 3b-1
                           w0 = wv3.y; w1 = wv3.z; w2 = wv3.w; }

        // fmaxf guard: numerically inert for real inputs (P(r2<1e-30)~0) but
        // blocks the only inf->NaN propagation path (rsq(0)=inf, 0*inf=NaN).
        const float r2   = fmaxf(x0 * x0 + x1 * x1 + x2 * x2, 1e-30f);
        const float invr = __builtin_amdgcn_rsqf(r2);   // 1/|x|
        const float r    = r2 * invr;                   // |x|

        const float p0 = x0 * invr + w0;
        const float p1 = x1 * invr + w1;
        const float p2 = x2 * invr + w2;

        const float wns  = w0 * w0 + w1 * w1 + w2 * w2;
        const float xwns = fmaxf(p0 * p0 + p1 * p1 + p2 * p2, 1e-30f);
        const float cc   = (1.0f - wns) * __builtin_amdgcn_rcpf(xwns);  // > 0

        // Transposed store to LDS: bank = (3*tid + j) mod 32, gcd(3,32)=1 ->
        // all 32 banks hit exactly twice per instruction -> conflict-free.
        const int b = tid + 256 * c;
        sy[3 * b]     = r * (cc * p0 + w0);
        sy[3 * b + 1] = r * (cc * p1 + w1);
        sy[3 * b + 2] = r * (cc * p2 + w2);

        lsum += __builtin_amdgcn_logf(cc);   // log2(c)
    }

    // Row reduction: wave shuffle (64 lanes) then cross-wave LDS.
    #pragma unroll
    for (int off = 32; off > 0; off >>= 1) {
        lsum += __shfl_down(lsum, off, 64);
    }
    const int lane = tid & 63;
    const int wave = tid >> 6;
    if (lane == 0) swred[wave] = lsum;
    __syncthreads();   // y fully staged in LDS + swred visible

    // Coalesced float4 stores from LDS (b128 reads at 16B stride: free).
    float4* __restrict__ y4 = (float4*)(out + rbase);
    const float4* __restrict__ s4 = (const float4*)sy;
    y4[tid]       = s4[tid];
    y4[tid + 256] = s4[tid + 256];
    y4[tid + 512] = s4[tid + 512];

    if (tid == 0) {
        const float tot = (swred[0] + swred[1] + swred[2] + swred[3]) * 1.3862943611f;
        out[(size_t)BATCH * FEAT + row] = tot;   // 2*ln2 * sum(log2 c)
    }
}

extern "C" void kernel_launch(void* const* d_in, const int* in_sizes, int n_in,
                              void* d_out, int out_size, void* d_ws, size_t ws_size,
                              hipStream_t stream) {
    const float* x = (const float*)d_in[0];
    const float* w = (const float*)d_in[1];
    float* out = (float*)d_out;   // [B*F] y followed by [B] log_det_J

    moebius_kernel<<<BATCH, TPB, 0, stream>>>(x, w, out);
}